// Round 18
// baseline (100.487 us; speedup 1.0000x reference)
//
#include <hip/hip_runtime.h>

#define HDIM 512
#define BM 64

typedef __attribute__((ext_vector_type(8))) short bf16x8;
typedef __attribute__((ext_vector_type(4))) float f32x4;

__device__ __forceinline__ unsigned short f2bf(float f){
  union { float f; unsigned int u; } c; c.f = f;
  unsigned int u = c.u;
  unsigned int r = u + 0x7fffu + ((u >> 16) & 1u);
  return (unsigned short)(r >> 16);
}
__device__ __forceinline__ float bf2f(unsigned short b){
  union { unsigned int u; float f; } c; c.u = ((unsigned int)b) << 16;
  return c.f;
}
// pack hi16 of two floats (truncation to bf16): out = [bf(b):bf(a)]
__device__ __forceinline__ unsigned int pack_trunc(float a, float b){
  return __builtin_amdgcn_perm(__float_as_uint(b), __float_as_uint(a), 0x07060302u);
}
// DPP-based 16-lane row sum (VALU only — no LDS pipe).
template<int CTRL>
__device__ __forceinline__ float dpp_add(float x){
  int y = __builtin_amdgcn_update_dpp(0, __float_as_int(x), CTRL, 0xf, 0xf, true);
  return x + __int_as_float(y);
}
__device__ __forceinline__ float row_sum16(float x){
  x = dpp_add<0xB1>(x);    // quad_perm xor1
  x = dpp_add<0x4E>(x);    // quad_perm xor2
  x = dpp_add<0x124>(x);   // row_ror:4
  x = dpp_add<0x128>(x);   // row_ror:8
  return x;
}

// ---------------- kernel 1: pack Wrh -> per-wave MFMA fragment order (bf16)
//                  + xwri = Wri @ x        (8 colgrps of 64 cols — R16 layout)
__global__ __launch_bounds__(256) void prep_k(const float* __restrict__ Wrh,
    unsigned short* __restrict__ wpack, const float* __restrict__ Wri,
    const float* __restrict__ x, float* __restrict__ xwri)
{
  int b = blockIdx.x;
  if (b < 128){
    int t    = b * 256 + threadIdx.x;   // 0..32767
    int lane = t & 63;
    int g    = t >> 6;                  // 0..511
    int ni   = g & 3;
    int kkk  = (g >> 2) & 15;
    int wc   = g >> 6;                  // 0..7
    int row  = wc * 64 + ni * 16 + (lane & 15);
    int k0   = kkk * 32 + (lane >> 4) * 8;
    const float* src = Wrh + (size_t)row * HDIM + k0;
    float4 f0 = *(const float4*)(src);
    float4 f1 = *(const float4*)(src + 4);
    bf16x8 v;
    v[0]=(short)f2bf(f0.x); v[1]=(short)f2bf(f0.y); v[2]=(short)f2bf(f0.z); v[3]=(short)f2bf(f0.w);
    v[4]=(short)f2bf(f1.x); v[5]=(short)f2bf(f1.y); v[6]=(short)f2bf(f1.z); v[7]=(short)f2bf(f1.w);
    *(bf16x8*)(wpack + (size_t)t * 8) = v;
  } else {
    int lane = threadIdx.x & 63, wid = threadIdx.x >> 6;
    int row = (b - 128) * 4 + wid;
    const float* Wr = Wri + (size_t)row * HDIM;
    float a = 0.f;
    #pragma unroll
    for (int k = 0; k < HDIM / 64; k++) a += x[k*64 + lane] * Wr[k*64 + lane];
    #pragma unroll
    for (int m = 1; m < 64; m <<= 1) a += __shfl_xor(a, m, 64);
    if (lane == 0) xwri[row] = a;
  }
}

// ---------------- kernel 2: fused GEMM + LN + sigmoid + partial sums ---------
// BM=64, 512 threads = 8 waves, each wave 64x64 (full rows of its 64 cols).
// TWO WGs co-resident per CU (LDS 68.5KB, __launch_bounds__(512,4) caps 128
// regs -> 16 waves/CU): one WG's serialized epilogue/staging overlaps the
// other's MFMA phases — the inter-WG overlap R6-R10 had, now combined with
// R16's conflict-free phase-major LDS + DPP stats + fast sigmoid.
// Phase-major As[8][64][64] bf16, 16B-granule XOR swizzle (conflict-free
// reads+writes, verified R12-R17: SQ_LDS_BANK_CONFLICT = 0). 8 barriers.
__global__ __launch_bounds__(512, 4) void fused_r(
    const float* __restrict__ hiddens,
    const unsigned short* __restrict__ wpack,
    const float* __restrict__ xWri,
    const float* __restrict__ gr, const float* __restrict__ br,
    float* __restrict__ psum_rh, float* __restrict__ psum_h)
{
  __shared__ short As[BM * HDIM];      // 64 KB, phase-major [8][64][64]
  __shared__ float redS[8 * 64];       // 2 KB
  __shared__ float redQ[8 * 64];       // 2 KB
  __shared__ float mu_s[64], rs_s[64];

  const int tid    = threadIdx.x;
  const int lane   = tid & 63;
  const int colgrp = tid >> 6;        // 0..7
  const int llo    = lane & 15;
  const int lhi    = lane >> 4;
  const int wcol   = colgrp * 64;
  const int r0     = blockIdx.x * BM;

  // staging: thread -> row tid>>3 (0..63), 8 f32 at col (tid&7)*8, 1 uint4/phase
  const int srow = tid >> 3;
  const int scs  = tid & 7;
  const float* aglob = hiddens + (size_t)(r0 + srow) * HDIM + scs * 8;
  char* const wptr = (char*)As + srow * 128 + ((scs * 16) ^ ((srow & 7) << 4));

  // frag read offset; phase p adds p*8192, mi adds mi*2048, ks1 applies ^64
  const int rdoff = llo * 128 + ((lhi * 16) ^ ((llo & 7) << 4));

  f32x4 acc[4][4];
  #pragma unroll
  for (int i = 0; i < 4; i++)
    #pragma unroll
    for (int j = 0; j < 4; j++)
      #pragma unroll
      for (int k = 0; k < 4; k++) acc[i][j][k] = 0.f;

  // ---- prologue: stage A phase 0; prefetch A phase 1
  const bf16x8* wp = (const bf16x8*)wpack + ((size_t)colgrp * 64) * 64 + lane;
  {
    float4 f0 = *(const float4*)(aglob);
    float4 f1 = *(const float4*)(aglob + 4);
    uint4 w;
    w.x = pack_trunc(f0.x, f0.y); w.y = pack_trunc(f0.z, f0.w);
    w.z = pack_trunc(f1.x, f1.y); w.w = pack_trunc(f1.z, f1.w);
    *(uint4*)(wptr) = w;
  }
  float4 pA0 = *(const float4*)(aglob + 64);
  float4 pA1 = *(const float4*)(aglob + 68);
  asm volatile("s_waitcnt lgkmcnt(0)" ::: "memory");
  __builtin_amdgcn_s_barrier();

  // ---- K loop: 8 phases of K=64 (2 sub-slices of K=32)
  #pragma unroll 1
  for (int p = 0; p < 8; p++){
    const int pb = p * 8192;
    // B ks0 (JIT) + A frags ks0
    bf16x8 bfr[4];
    #pragma unroll
    for (int ni = 0; ni < 4; ni++) bfr[ni] = wp[(2 * p) * 256 + ni * 64];
    bf16x8 af[4];
    #pragma unroll
    for (int mi = 0; mi < 4; mi++)
      af[mi] = *(const bf16x8*)((char*)As + (pb + rdoff + mi * 2048));
    // stage phase p+1 from prefetched registers
    if (p < 7){
      uint4 w;
      w.x = pack_trunc(pA0.x, pA0.y); w.y = pack_trunc(pA0.z, pA0.w);
      w.z = pack_trunc(pA1.x, pA1.y); w.w = pack_trunc(pA1.z, pA1.w);
      *(uint4*)(wptr + (p + 1) * 8192) = w;
    }
    // global prefetch phase p+2
    if (p < 6){
      pA0 = *(const float4*)(aglob + (p + 2) * 64);
      pA1 = *(const float4*)(aglob + (p + 2) * 64 + 4);
    }
    // MFMA ks0
    __builtin_amdgcn_s_setprio(1);
    #pragma unroll
    for (int mi = 0; mi < 4; mi++)
      #pragma unroll
      for (int ni = 0; ni < 4; ni++)
        acc[mi][ni] = __builtin_amdgcn_mfma_f32_16x16x32_bf16(af[mi], bfr[ni], acc[mi][ni], 0, 0, 0);
    __builtin_amdgcn_s_setprio(0);
    // B ks1 (JIT, reuses bfr) + A frags ks1 (reuses af, addr ^64)
    #pragma unroll
    for (int ni = 0; ni < 4; ni++) bfr[ni] = wp[(2 * p + 1) * 256 + ni * 64];
    #pragma unroll
    for (int mi = 0; mi < 4; mi++)
      af[mi] = *(const bf16x8*)((char*)As + ((pb + rdoff + mi * 2048) ^ 64));
    // MFMA ks1
    __builtin_amdgcn_s_setprio(1);
    #pragma unroll
    for (int mi = 0; mi < 4; mi++)
      #pragma unroll
      for (int ni = 0; ni < 4; ni++)
        acc[mi][ni] = __builtin_amdgcn_mfma_f32_16x16x32_bf16(af[mi], bfr[ni], acc[mi][ni], 0, 0, 0);
    __builtin_amdgcn_s_setprio(0);
    asm volatile("s_waitcnt lgkmcnt(0)" ::: "memory");
    __builtin_amdgcn_s_barrier();
  }

  // ---- add xWri, per-row LN stats (DPP row-sum; cross-colgrp via LDS)
  float xw[4], g4[4], b4[4];
  #pragma unroll
  for (int ni = 0; ni < 4; ni++){
    int c = wcol + ni * 16 + llo;
    xw[ni] = xWri[c];
    g4[ni] = gr[c];
    b4[ni] = br[c];
  }
  #pragma unroll
  for (int mi = 0; mi < 4; mi++){
    #pragma unroll
    for (int rr = 0; rr < 4; rr++){
      float sv = 0.f, qv = 0.f;
      #pragma unroll
      for (int ni = 0; ni < 4; ni++){
        float v = acc[mi][ni][rr] + xw[ni];
        acc[mi][ni][rr] = v;
        sv += v; qv += v * v;
      }
      sv = row_sum16(sv);
      qv = row_sum16(qv);
      if (llo == 0){
        int row = mi * 16 + lhi * 4 + rr;   // 0..63
        redS[colgrp * 64 + row] = sv;
        redQ[colgrp * 64 + row] = qv;
      }
    }
  }
  __syncthreads();
  if (tid < 64){
    float S = 0.f, Q = 0.f;
    #pragma unroll
    for (int w = 0; w < 8; w++){ S += redS[w * 64 + tid]; Q += redQ[w * 64 + tid]; }
    float mu  = S * (1.f / 512.f);
    float var = Q * (1.f / 512.f) - mu * mu;
    mu_s[tid] = mu;
    rs_s[tid] = rsqrtf(var + 1e-5f);
  }
  __syncthreads();

  // ---- r = sigmoid(LN(v)); psums from h (bf16) in As; direct psum write
  float prh[4] = {0.f, 0.f, 0.f, 0.f};
  float ph [4] = {0.f, 0.f, 0.f, 0.f};
  #pragma unroll
  for (int mi = 0; mi < 4; mi++){
    #pragma unroll
    for (int rr = 0; rr < 4; rr++){
      int row = mi * 16 + lhi * 4 + rr;
      float mu = mu_s[row], rs = rs_s[row];
      int sw2 = (row & 7) << 4;
      #pragma unroll
      for (int ni = 0; ni < 4; ni++){
        float v = (acc[mi][ni][rr] - mu) * rs * g4[ni] + b4[ni];
        float r = __builtin_amdgcn_rcpf(1.f + __expf(-v));
        int cb = ni * 32 + llo * 2;              // col byte within phase row
        float h = bf2f(*(const unsigned short*)((char*)As + colgrp * 8192
                     + row * 128 + (cb ^ sw2)));
        prh[ni] += r * h;
        ph [ni] += h;
      }
    }
  }
  #pragma unroll
  for (int ni = 0; ni < 4; ni++){
    prh[ni] += __shfl_xor(prh[ni], 16, 64);
    prh[ni] += __shfl_xor(prh[ni], 32, 64);
    ph [ni] += __shfl_xor(ph [ni], 16, 64);
    ph [ni] += __shfl_xor(ph [ni], 32, 64);
  }
  if (lhi == 0){
    #pragma unroll
    for (int ni = 0; ni < 4; ni++){
      int col = wcol + ni * 16 + llo;
      psum_rh[(size_t)blockIdx.x * HDIM + col] = prh[ni];
      psum_h [(size_t)blockIdx.x * HDIM + col] = ph[ni];
    }
  }
}

// ---------------- kernel 3: reduce partials, build cat vectors ---------------
__global__ __launch_bounds__(256) void reduce_psums(
    const float* __restrict__ psum_rh, const float* __restrict__ psum_h,
    const float* __restrict__ x, float* __restrict__ catz, float* __restrict__ catu,
    int nblk)
{
  __shared__ float L[8][32];
  int b = blockIdx.x, t = threadIdx.x;
  if (b < 32){
    const float* P = (b < 16) ? psum_rh : psum_h;
    int c0 = (b & 15) * 32;
    int wj = t >> 5, ci = t & 31;
    float a = 0.f;
    for (int s = wj; s < nblk; s += 8) a += P[(size_t)s * 512 + c0 + ci];
    L[wj][ci] = a;
    __syncthreads();
    if (t < 32){
      float r = 0.f;
      #pragma unroll
      for (int w = 0; w < 8; w++) r += L[w][t];
      if (b < 16) catu[512 + c0 + t] = r;   // (r*hiddens).sum(0)
      else        catz[512 + c0 + t] = r;   // hidden_sum
    }
  } else {
    int i = ((b - 32) & 1) * 256 + t;       // 0..511
    if (b < 34) catz[i] = x[i];
    else        catu[i] = x[i];
  }
}

// ---------------- kernel 4: zpre = Wz@catz, upre = Wu@catu (one launch) ------
__global__ __launch_bounds__(256) void matvec_zu(
    const float* __restrict__ Wz, const float* __restrict__ Wu,
    const float* __restrict__ catz, const float* __restrict__ catu,
    float* __restrict__ zpre, float* __restrict__ upre)
{
  int b = blockIdx.x, lane = threadIdx.x & 63, wid = threadIdx.x >> 6;
  int row = (b & 127) * 4 + wid;
  const float* W = (b < 128) ? Wz : Wu;
  const float* v = (b < 128) ? catz : catu;
  float*       o = (b < 128) ? zpre : upre;
  const float* Wr = W + (size_t)row * 1024;
  float a = 0.f;
  #pragma unroll
  for (int k = 0; k < 1024 / 64; k++) a += v[k*64 + lane] * Wr[k*64 + lane];
  #pragma unroll
  for (int m = 1; m < 64; m <<= 1) a += __shfl_xor(a, m, 64);
  if (lane == 0) o[row] = a;
}

// ---------------- kernel 5: final LN + gates + output ------------------------
__global__ __launch_bounds__(512) void finalize_k(
    const float* __restrict__ zpre, const float* __restrict__ upre,
    const float* __restrict__ gz, const float* __restrict__ bz,
    const float* __restrict__ gu, const float* __restrict__ bu,
    const float* __restrict__ catz, float* __restrict__ out)
{
  __shared__ float R[8][4];
  int t = threadIdx.x, lane = t & 63, wid = t >> 6;
  float zp = zpre[t], up = upre[t];
  float zs = zp, zq = zp * zp, us = up, uq = up * up;
  #pragma unroll
  for (int m = 1; m < 64; m <<= 1){
    zs += __shfl_xor(zs, m, 64); zq += __shfl_xor(zq, m, 64);
    us += __shfl_xor(us, m, 64); uq += __shfl_xor(uq, m, 64);
  }
  if (lane == 0){ R[wid][0] = zs; R[wid][1] = zq; R[wid][2] = us; R[wid][3] = uq; }
  __syncthreads();
  float ZS = 0.f, ZQ = 0.f, US = 0.f, UQ = 0.f;
  #pragma unroll
  for (int w = 0; w < 8; w++){ ZS += R[w][0]; ZQ += R[w][1]; US += R[w][2]; UQ += R[w][3]; }
  float zmu = ZS / 512.f, zrs = rsqrtf(ZQ / 512.f - zmu * zmu + 1e-5f);
  float umu = US / 512.f, urs = rsqrtf(UQ / 512.f - umu * umu + 1e-5f);
  float z = 1.f / (1.f + expf(-((zp - zmu) * zrs * gz[t] + bz[t])));
  float u = tanhf((up - umu) * urs * gu[t] + bu[t]);
  float hs = catz[512 + t];
  out[t] = z * hs + (1.f - z) * u;
}

// -----------------------------------------------------------------------------
extern "C" void kernel_launch(void* const* d_in, const int* in_sizes, int n_in,
                              void* d_out, int out_size, void* d_ws, size_t ws_size,
                              hipStream_t stream)
{
  const float* x   = (const float*)d_in[0];
  const float* hid = (const float*)d_in[1];
  const float* Wz  = (const float*)d_in[2];
  const float* Wri = (const float*)d_in[3];
  const float* Wrh = (const float*)d_in[4];
  const float* Wu  = (const float*)d_in[5];
  const float* gz  = (const float*)d_in[6];
  const float* bz  = (const float*)d_in[7];
  const float* gr  = (const float*)d_in[8];
  const float* br  = (const float*)d_in[9];
  const float* gu  = (const float*)d_in[10];
  const float* bu  = (const float*)d_in[11];
  (void)n_in; (void)out_size; (void)ws_size;

  const int M    = in_sizes[1] / HDIM;   // 65536
  const int nblk = M / BM;               // 1024

  char* ws = (char*)d_ws;
  unsigned short* wpack = (unsigned short*)ws;              // 512 KB
  float* xwri    = (float*)(ws + 524288);                   // 2 KB
  float* psum_rh = (float*)(ws + 526336);                   // nblk*512*4
  float* psum_h  = (float*)(ws + 526336 + (size_t)nblk * 2048);
  char*  p2      = ws + 526336 + (size_t)nblk * 4096;
  float* catz    = (float*)p2;                              // 4 KB
  float* catu    = (float*)(p2 + 4096);                     // 4 KB
  float* zpre    = (float*)(p2 + 8192);                     // 2 KB
  float* upre    = (float*)(p2 + 10240);                    // 2 KB
  float* out     = (float*)d_out;

  hipLaunchKernelGGL(prep_k,       dim3(256),  dim3(256), 0, stream, Wrh, wpack, Wri, x, xwri);
  hipLaunchKernelGGL(fused_r,      dim3(nblk), dim3(512), 0, stream, hid, wpack, xwri, gr, br, psum_rh, psum_h);
  hipLaunchKernelGGL(reduce_psums, dim3(36),   dim3(256), 0, stream, psum_rh, psum_h, x, catz, catu, nblk);
  hipLaunchKernelGGL(matvec_zu,    dim3(256),  dim3(256), 0, stream, Wz, Wu, catz, catu, zpre, upre);
  hipLaunchKernelGGL(finalize_k,   dim3(1),    dim3(512), 0, stream, zpre, upre, gz, bz, gu, bu, catz, out);
}

// Round 21
// 89.506 us; speedup vs baseline: 1.1227x; 1.1227x over previous
//
#include <hip/hip_runtime.h>

#define HDIM 512
#define BM 128

typedef __attribute__((ext_vector_type(8))) short bf16x8;
typedef __attribute__((ext_vector_type(4))) float f32x4;

__device__ __forceinline__ unsigned short f2bf(float f){
  union { float f; unsigned int u; } c; c.f = f;
  unsigned int u = c.u;
  unsigned int r = u + 0x7fffu + ((u >> 16) & 1u);
  return (unsigned short)(r >> 16);
}
__device__ __forceinline__ float bf2f(unsigned short b){
  union { unsigned int u; float f; } c; c.u = ((unsigned int)b) << 16;
  return c.f;
}
// pack hi16 of two floats (truncation to bf16): out = [bf(b):bf(a)]
__device__ __forceinline__ unsigned int pack_trunc(float a, float b){
  return __builtin_amdgcn_perm(__float_as_uint(b), __float_as_uint(a), 0x07060302u);
}
// DPP-based 16-lane row sum (VALU only — no LDS pipe, no ds_bpermute).
template<int CTRL>
__device__ __forceinline__ float dpp_add(float x){
  int y = __builtin_amdgcn_update_dpp(0, __float_as_int(x), CTRL, 0xf, 0xf, true);
  return x + __int_as_float(y);
}
__device__ __forceinline__ float row_sum16(float x){
  x = dpp_add<0xB1>(x);    // quad_perm xor1
  x = dpp_add<0x4E>(x);    // quad_perm xor2
  x = dpp_add<0x124>(x);   // row_ror:4
  x = dpp_add<0x128>(x);   // row_ror:8
  return x;
}

// ---------------- kernel 1: pack Wrh -> per-wave MFMA fragment order (bf16)
//                  + xwri = Wri @ x
__global__ __launch_bounds__(256) void prep_k(const float* __restrict__ Wrh,
    unsigned short* __restrict__ wpack, const float* __restrict__ Wri,
    const float* __restrict__ x, float* __restrict__ xwri)
{
  int b = blockIdx.x;
  if (b < 128){
    int t    = b * 256 + threadIdx.x;   // 0..32767
    int lane = t & 63;
    int g    = t >> 6;                  // 0..511
    int ni   = g & 3;
    int kkk  = (g >> 2) & 15;
    int wc   = g >> 6;
    int row  = wc * 64 + ni * 16 + (lane & 15);
    int k0   = kkk * 32 + (lane >> 4) * 8;
    const float* src = Wrh + (size_t)row * HDIM + k0;
    float4 f0 = *(const float4*)(src);
    float4 f1 = *(const float4*)(src + 4);
    bf16x8 v;
    v[0]=(short)f2bf(f0.x); v[1]=(short)f2bf(f0.y); v[2]=(short)f2bf(f0.z); v[3]=(short)f2bf(f0.w);
    v[4]=(short)f2bf(f1.x); v[5]=(short)f2bf(f1.y); v[6]=(short)f2bf(f1.z); v[7]=(short)f2bf(f1.w);
    *(bf16x8*)(wpack + (size_t)t * 8) = v;
  } else {
    int lane = threadIdx.x & 63, wid = threadIdx.x >> 6;
    int row = (b - 128) * 4 + wid;
    const float* Wr = Wri + (size_t)row * HDIM;
    float a = 0.f;
    #pragma unroll
    for (int k = 0; k < HDIM / 64; k++) a += x[k*64 + lane] * Wr[k*64 + lane];
    #pragma unroll
    for (int m = 1; m < 64; m <<= 1) a += __shfl_xor(a, m, 64);
    if (lane == 0) xwri[row] = a;
  }
}

// ---------------- kernel 2: fused GEMM + LN + sigmoid + partial sums ---------
// BM=128, 1024 threads = 16 waves (2 rowgrp x 8 colgrp), each wave 64x64.
// Phase-major A LDS: As[8][128 rows][64 cols] bf16, 16B-granule XOR swizzle
// -> conflict-free b128 reads AND uint4 staging writes (verified R12-R16:
// SQ_LDS_BANK_CONFLICT = 0). 8 barriers (K=64/phase). No spill (WRITE ~2MB).
// DPP stats reduce (VALU, no DS pipe). Fast sigmoid via rcp+exp2. JIT B loads.
// Measured best of the structure family: 89.9 us official (R16).
__global__ __launch_bounds__(1024, 4) void fused_r(
    const float* __restrict__ hiddens,
    const unsigned short* __restrict__ wpack,
    const float* __restrict__ xWri,
    const float* __restrict__ gr, const float* __restrict__ br,
    float* __restrict__ psum_rh, float* __restrict__ psum_h)
{
  __shared__ short As[BM * HDIM];      // 128 KB, phase-major
  __shared__ float redS[8 * 128];      // 4 KB; reused as ppRH in epilogue
  __shared__ float redQ[8 * 128];      // 4 KB; reused as ppH
  __shared__ float mu_s[128], rs_s[128];

  const int tid    = threadIdx.x;
  const int lane   = tid & 63;
  const int wid    = tid >> 6;        // 0..15
  const int rowgrp = wid >> 3;        // 0..1
  const int colgrp = wid & 7;         // 0..7
  const int llo    = lane & 15;
  const int lhi    = lane >> 4;
  const int wcol   = colgrp * 64;
  const int rbase  = rowgrp * 64;
  const int r0     = blockIdx.x * BM;

  // staging: thread -> row tid>>3 (0..127), 8 f32 at col (tid&7)*8, 1 uint4/phase
  const int srow = tid >> 3;
  const int scs  = tid & 7;
  const float* aglob = hiddens + (size_t)(r0 + srow) * HDIM + scs * 8;
  char* const wptr = (char*)As + srow * 128 + ((scs * 16) ^ ((srow & 7) << 4));

  // frag read offset (bytes within As); phase p adds p*16384, mi adds mi*2048,
  // ks1 applies ^64 (exact: granule(4+lhi) = granule(lhi)^4)
  const int rdoff = (rbase + llo) * 128 + ((lhi * 16) ^ ((llo & 7) << 4));

  f32x4 acc[4][4];
  #pragma unroll
  for (int i = 0; i < 4; i++)
    #pragma unroll
    for (int j = 0; j < 4; j++)
      #pragma unroll
      for (int k = 0; k < 4; k++) acc[i][j][k] = 0.f;

  // ---- prologue: stage A phase 0; prefetch A phase 1
  const bf16x8* wp = (const bf16x8*)wpack + ((size_t)colgrp * 64) * 64 + lane;
  {
    float4 f0 = *(const float4*)(aglob);
    float4 f1 = *(const float4*)(aglob + 4);
    uint4 w;
    w.x = pack_trunc(f0.x, f0.y); w.y = pack_trunc(f0.z, f0.w);
    w.z = pack_trunc(f1.x, f1.y); w.w = pack_trunc(f1.z, f1.w);
    *(uint4*)(wptr) = w;
  }
  float4 pA0 = *(const float4*)(aglob + 64);
  float4 pA1 = *(const float4*)(aglob + 68);
  asm volatile("s_waitcnt lgkmcnt(0)" ::: "memory");
  __builtin_amdgcn_s_barrier();

  // ---- K loop: 8 phases of K=64 (2 sub-slices of K=32)
  #pragma unroll 1
  for (int p = 0; p < 8; p++){
    const int pb = p * 16384;
    // B ks0 (JIT) + A frags ks0
    bf16x8 bfr[4];
    #pragma unroll
    for (int ni = 0; ni < 4; ni++) bfr[ni] = wp[(2 * p) * 256 + ni * 64];
    bf16x8 af[4];
    #pragma unroll
    for (int mi = 0; mi < 4; mi++)
      af[mi] = *(const bf16x8*)((char*)As + (pb + rdoff + mi * 2048));
    // stage phase p+1 from prefetched registers
    if (p < 7){
      uint4 w;
      w.x = pack_trunc(pA0.x, pA0.y); w.y = pack_trunc(pA0.z, pA0.w);
      w.z = pack_trunc(pA1.x, pA1.y); w.w = pack_trunc(pA1.z, pA1.w);
      *(uint4*)(wptr + (p + 1) * 16384) = w;
    }
    // global prefetch phase p+2
    if (p < 6){
      pA0 = *(const float4*)(aglob + (p + 2) * 64);
      pA1 = *(const float4*)(aglob + (p + 2) * 64 + 4);
    }
    // MFMA ks0
    __builtin_amdgcn_s_setprio(1);
    #pragma unroll
    for (int mi = 0; mi < 4; mi++)
      #pragma unroll
      for (int ni = 0; ni < 4; ni++)
        acc[mi][ni] = __builtin_amdgcn_mfma_f32_16x16x32_bf16(af[mi], bfr[ni], acc[mi][ni], 0, 0, 0);
    __builtin_amdgcn_s_setprio(0);
    // B ks1 (JIT, reuses bfr) + A frags ks1 (reuses af, addr ^64)
    #pragma unroll
    for (int ni = 0; ni < 4; ni++) bfr[ni] = wp[(2 * p + 1) * 256 + ni * 64];
    #pragma unroll
    for (int mi = 0; mi < 4; mi++)
      af[mi] = *(const bf16x8*)((char*)As + ((pb + rdoff + mi * 2048) ^ 64));
    // MFMA ks1
    __builtin_amdgcn_s_setprio(1);
    #pragma unroll
    for (int mi = 0; mi < 4; mi++)
      #pragma unroll
      for (int ni = 0; ni < 4; ni++)
        acc[mi][ni] = __builtin_amdgcn_mfma_f32_16x16x32_bf16(af[mi], bfr[ni], acc[mi][ni], 0, 0, 0);
    __builtin_amdgcn_s_setprio(0);
    asm volatile("s_waitcnt lgkmcnt(0)" ::: "memory");
    __builtin_amdgcn_s_barrier();
  }

  // ---- add xWri, per-row LN stats (DPP row-sum; cross-colgrp via LDS)
  float xw[4], g4[4], b4[4];
  #pragma unroll
  for (int ni = 0; ni < 4; ni++){
    int c = wcol + ni * 16 + llo;
    xw[ni] = xWri[c];
    g4[ni] = gr[c];
    b4[ni] = br[c];
  }
  #pragma unroll
  for (int mi = 0; mi < 4; mi++){
    #pragma unroll
    for (int rr = 0; rr < 4; rr++){
      float sv = 0.f, qv = 0.f;
      #pragma unroll
      for (int ni = 0; ni < 4; ni++){
        float v = acc[mi][ni][rr] + xw[ni];
        acc[mi][ni][rr] = v;
        sv += v; qv += v * v;
      }
      sv = row_sum16(sv);
      qv = row_sum16(qv);
      if (llo == 0){
        int row = rbase + mi * 16 + lhi * 4 + rr;   // 0..127
        redS[colgrp * 128 + row] = sv;
        redQ[colgrp * 128 + row] = qv;
      }
    }
  }
  __syncthreads();
  if (tid < 128){
    float S = 0.f, Q = 0.f;
    #pragma unroll
    for (int w = 0; w < 8; w++){ S += redS[w * 128 + tid]; Q += redQ[w * 128 + tid]; }
    float mu  = S * (1.f / 512.f);
    float var = Q * (1.f / 512.f) - mu * mu;
    mu_s[tid] = mu;
    rs_s[tid] = rsqrtf(var + 1e-5f);
  }
  __syncthreads();

  // ---- r = sigmoid(LN(v)); psums from h (bf16) in As (phase = colgrp)
  float prh[4] = {0.f, 0.f, 0.f, 0.f};
  float ph [4] = {0.f, 0.f, 0.f, 0.f};
  #pragma unroll
  for (int mi = 0; mi < 4; mi++){
    #pragma unroll
    for (int rr = 0; rr < 4; rr++){
      int row = rbase + mi * 16 + lhi * 4 + rr;
      float mu = mu_s[row], rs = rs_s[row];
      int sw2 = (row & 7) << 4;
      #pragma unroll
      for (int ni = 0; ni < 4; ni++){
        float v = (acc[mi][ni][rr] - mu) * rs * g4[ni] + b4[ni];
        float r = __builtin_amdgcn_rcpf(1.f + __expf(-v));
        int cb = ni * 32 + llo * 2;              // col byte within phase row
        float h = bf2f(*(const unsigned short*)((char*)As + colgrp * 16384
                     + row * 128 + (cb ^ sw2)));
        prh[ni] += r * h;
        ph [ni] += h;
      }
    }
  }
  #pragma unroll
  for (int ni = 0; ni < 4; ni++){
    prh[ni] += __shfl_xor(prh[ni], 16, 64);
    prh[ni] += __shfl_xor(prh[ni], 32, 64);
    ph [ni] += __shfl_xor(ph [ni], 16, 64);
    ph [ni] += __shfl_xor(ph [ni], 32, 64);
  }
  // cross-rowgroup combine via reused redS/redQ (stats phase done)
  float* ppRH = redS;   // [2][512]
  float* ppH  = redQ;   // [2][512]
  if (lhi == 0){
    #pragma unroll
    for (int ni = 0; ni < 4; ni++){
      int col = wcol + ni * 16 + llo;
      ppRH[rowgrp * 512 + col] = prh[ni];
      ppH [rowgrp * 512 + col] = ph[ni];
    }
  }
  __syncthreads();
  if (tid < 512){
    psum_rh[(size_t)blockIdx.x * HDIM + tid] = ppRH[tid] + ppRH[512 + tid];
    psum_h [(size_t)blockIdx.x * HDIM + tid] = ppH[tid]  + ppH[512 + tid];
  }
}

// ---------------- kernel 3: reduce partials, build cat vectors ---------------
__global__ __launch_bounds__(256) void reduce_psums(
    const float* __restrict__ psum_rh, const float* __restrict__ psum_h,
    const float* __restrict__ x, float* __restrict__ catz, float* __restrict__ catu,
    int nblk)
{
  __shared__ float L[8][32];
  int b = blockIdx.x, t = threadIdx.x;
  if (b < 32){
    const float* P = (b < 16) ? psum_rh : psum_h;
    int c0 = (b & 15) * 32;
    int wj = t >> 5, ci = t & 31;
    float a = 0.f;
    for (int s = wj; s < nblk; s += 8) a += P[(size_t)s * 512 + c0 + ci];
    L[wj][ci] = a;
    __syncthreads();
    if (t < 32){
      float r = 0.f;
      #pragma unroll
      for (int w = 0; w < 8; w++) r += L[w][t];
      if (b < 16) catu[512 + c0 + t] = r;   // (r*hiddens).sum(0)
      else        catz[512 + c0 + t] = r;   // hidden_sum
    }
  } else {
    int i = ((b - 32) & 1) * 256 + t;       // 0..511
    if (b < 34) catz[i] = x[i];
    else        catu[i] = x[i];
  }
}

// ---------------- kernel 4: zpre = Wz@catz, upre = Wu@catu (one launch) ------
__global__ __launch_bounds__(256) void matvec_zu(
    const float* __restrict__ Wz, const float* __restrict__ Wu,
    const float* __restrict__ catz, const float* __restrict__ catu,
    float* __restrict__ zpre, float* __restrict__ upre)
{
  int b = blockIdx.x, lane = threadIdx.x & 63, wid = threadIdx.x >> 6;
  int row = (b & 127) * 4 + wid;
  const float* W = (b < 128) ? Wz : Wu;
  const float* v = (b < 128) ? catz : catu;
  float*       o = (b < 128) ? zpre : upre;
  const float* Wr = W + (size_t)row * 1024;
  float a = 0.f;
  #pragma unroll
  for (int k = 0; k < 1024 / 64; k++) a += v[k*64 + lane] * Wr[k*64 + lane];
  #pragma unroll
  for (int m = 1; m < 64; m <<= 1) a += __shfl_xor(a, m, 64);
  if (lane == 0) o[row] = a;
}

// ---------------- kernel 5: final LN + gates + output ------------------------
__global__ __launch_bounds__(512) void finalize_k(
    const float* __restrict__ zpre, const float* __restrict__ upre,
    const float* __restrict__ gz, const float* __restrict__ bz,
    const float* __restrict__ gu, const float* __restrict__ bu,
    const float* __restrict__ catz, float* __restrict__ out)
{
  __shared__ float R[8][4];
  int t = threadIdx.x, lane = t & 63, wid = t >> 6;
  float zp = zpre[t], up = upre[t];
  float zs = zp, zq = zp * zp, us = up, uq = up * up;
  #pragma unroll
  for (int m = 1; m < 64; m <<= 1){
    zs += __shfl_xor(zs, m, 64); zq += __shfl_xor(zq, m, 64);
    us += __shfl_xor(us, m, 64); uq += __shfl_xor(uq, m, 64);
  }
  if (lane == 0){ R[wid][0] = zs; R[wid][1] = zq; R[wid][2] = us; R[wid][3] = uq; }
  __syncthreads();
  float ZS = 0.f, ZQ = 0.f, US = 0.f, UQ = 0.f;
  #pragma unroll
  for (int w = 0; w < 8; w++){ ZS += R[w][0]; ZQ += R[w][1]; US += R[w][2]; UQ += R[w][3]; }
  float zmu = ZS / 512.f, zrs = rsqrtf(ZQ / 512.f - zmu * zmu + 1e-5f);
  float umu = US / 512.f, urs = rsqrtf(UQ / 512.f - umu * umu + 1e-5f);
  float z = 1.f / (1.f + expf(-((zp - zmu) * zrs * gz[t] + bz[t])));
  float u = tanhf((up - umu) * urs * gu[t] + bu[t]);
  float hs = catz[512 + t];
  out[t] = z * hs + (1.f - z) * u;
}

// -----------------------------------------------------------------------------
extern "C" void kernel_launch(void* const* d_in, const int* in_sizes, int n_in,
                              void* d_out, int out_size, void* d_ws, size_t ws_size,
                              hipStream_t stream)
{
  const float* x   = (const float*)d_in[0];
  const float* hid = (const float*)d_in[1];
  const float* Wz  = (const float*)d_in[2];
  const float* Wri = (const float*)d_in[3];
  const float* Wrh = (const float*)d_in[4];
  const float* Wu  = (const float*)d_in[5];
  const float* gz  = (const float*)d_in[6];
  const float* bz  = (const float*)d_in[7];
  const float* gr  = (const float*)d_in[8];
  const float* br  = (const float*)d_in[9];
  const float* gu  = (const float*)d_in[10];
  const float* bu  = (const float*)d_in[11];
  (void)n_in; (void)out_size; (void)ws_size;

  const int M    = in_sizes[1] / HDIM;   // 65536
  const int nblk = M / BM;               // 512

  char* ws = (char*)d_ws;
  unsigned short* wpack = (unsigned short*)ws;              // 512 KB
  float* xwri    = (float*)(ws + 524288);                   // 2 KB
  float* psum_rh = (float*)(ws + 526336);                   // nblk*512*4
  float* psum_h  = (float*)(ws + 526336 + (size_t)nblk * 2048);
  char*  p2      = ws + 526336 + (size_t)nblk * 4096;
  float* catz    = (float*)p2;                              // 4 KB
  float* catu    = (float*)(p2 + 4096);                     // 4 KB
  float* zpre    = (float*)(p2 + 8192);                     // 2 KB
  float* upre    = (float*)(p2 + 10240);                    // 2 KB
  float* out     = (float*)d_out;

  hipLaunchKernelGGL(prep_k,       dim3(256),  dim3(256),  0, stream, Wrh, wpack, Wri, x, xwri);
  hipLaunchKernelGGL(fused_r,      dim3(nblk), dim3(1024), 0, stream, hid, wpack, xwri, gr, br, psum_rh, psum_h);
  hipLaunchKernelGGL(reduce_psums, dim3(36),   dim3(256),  0, stream, psum_rh, psum_h, x, catz, catu, nblk);
  hipLaunchKernelGGL(matvec_zu,    dim3(256),  dim3(256),  0, stream, Wz, Wu, catz, catu, zpre, upre);
  hipLaunchKernelGGL(finalize_k,   dim3(1),    dim3(512),  0, stream, zpre, upre, gz, bz, gu, bu, catz, out);
}